// Round 12
// baseline (234.741 us; speedup 1.0000x reference)
//
#include <hip/hip_runtime.h>
#include <hip/hip_fp16.h>

#define N_NODES 50000
#define N_EDGES 800000

typedef __attribute__((ext_vector_type(8))) short bf16x8;
typedef __attribute__((ext_vector_type(4))) float f32x4;

// ---------------- workspace layout (bytes) ----------------
#define OFF_BUFA   0UL          // 25,600,000  agg output fp32 [50000][128]
#define OFF_T16    25600000UL   // 12,800,000  fp16 feature table [50000][128]
#define OFF_CNT    38400000UL   //    200,000  degree counts
#define OFF_W      38600064UL   //    360,448  bf16 hi/lo weight pool (16B aligned)
#define OFF_CSR    38960512UL   //  6,400,000  padded CSR, ushort, 64 slots/node

#define NB_EDGE 3125   // 800000/256
#define NB_W    352    // 90112/256
#define NB_FEAT 6250   // 6,400,000/(256*4)

#define BM 160         // rows per MLP block
#define GB_MLP 313     // ceil(50000/160)

__device__ __forceinline__ unsigned short bf16_rne(float f) {
  unsigned u = __float_as_uint(f);
  unsigned r = (u + 0x7FFFu + ((u >> 16) & 1u)) >> 16;
  return (unsigned short)r;
}

__device__ __forceinline__ int swz(int row, int b) {
  return (row * 256 + b) ^ ((row & 7) << 4);
}

// async global->LDS, 16B per lane, LDS dst = uniform base + lane*16
__device__ __forceinline__ void gload_lds16(const void* g, void* l) {
  __builtin_amdgcn_global_load_lds(
      (const __attribute__((address_space(1))) unsigned int*)g,
      (__attribute__((address_space(3))) unsigned int*)l, 16, 0, 0);
}

// ---------------- scatter: padded ushort CSR ----------------
__global__ __launch_bounds__(256)
void scatter16(const int* __restrict__ src, const int* __restrict__ dst,
               int* __restrict__ cnt, unsigned short* __restrict__ csr) {
  int i = blockIdx.x * 256 + threadIdx.x;   // grid exactly covers 800000
  int d = dst[i];
  int pos = atomicAdd(&cnt[d], 1);
  if (pos < 64) csr[(d << 6) + pos] = (unsigned short)src[i];
}

// ---------------- conv: weights -> bf16 hi/lo pool, feat -> fp16 table ----------------
__global__ __launch_bounds__(256)
void conv_kernel(const float* __restrict__ W1a, const float* __restrict__ W1b,
                 const float* __restrict__ W2a, const float* __restrict__ W2b,
                 const float* __restrict__ W3a, const float* __restrict__ W3b,
                 unsigned short* __restrict__ pool,
                 const float* __restrict__ feat, __half* __restrict__ t16) {
  const int b = blockIdx.x;
  const int tid = threadIdx.x;
  if (b < NB_W) {
    int i = b * 256 + tid;                  // covers 90112
    const float* s;
    int base, local, msize;
    if (i < 16384)      { s = W1a; base = 0;      local = i;          msize = 16384; }
    else if (i < 32768) { s = W1b; base = 32768;  local = i - 16384;  msize = 16384; }
    else if (i < 49152) { s = W2a; base = 65536;  local = i - 32768;  msize = 16384; }
    else if (i < 65536) { s = W2b; base = 98304;  local = i - 49152;  msize = 16384; }
    else if (i < 81920) { s = W3a; base = 131072; local = i - 65536;  msize = 16384; }
    else                { s = W3b; base = 163840; local = i - 81920;  msize = 8192;  }
    float f = s[local];
    unsigned short hi = bf16_rne(f);
    float fh = __uint_as_float((unsigned)hi << 16);
    pool[base + local] = hi;
    pool[base + msize + local] = bf16_rne(f - fh);
  } else {
    int i = (b - NB_W) * 1024 + tid * 4;    // covers 6,400,000
    float4 v = *reinterpret_cast<const float4*>(feat + i);
    ushort4 h;
    h.x = __half_as_ushort(__float2half_rn(v.x));
    h.y = __half_as_ushort(__float2half_rn(v.y));
    h.z = __half_as_ushort(__float2half_rn(v.z));
    h.w = __half_as_ushort(__float2half_rn(v.w));
    *reinterpret_cast<ushort4*>((unsigned short*)t16 + i) = h;
  }
}

// ---------------- aggregation: out[v] = self[v] + inv_deg * sum t16[src]  (fp32 out) ----------------
template <bool SELF32>
__global__ __launch_bounds__(256)
void agg_kernel(const __half* __restrict__ t16, const float* __restrict__ xself,
                const unsigned short* __restrict__ csr, const int* __restrict__ cnt,
                float* __restrict__ out) {
  int node = blockIdx.x * 4 + (threadIdx.x >> 6);
  if (node >= N_NODES) return;
  const int lane = threadIdx.x & 63;
  int deg = cnt[node];
  int dloop = min(deg, 64);
  int beg = node << 6;
  float inv = 1.0f / fmaxf((float)deg, 1.0f);

  float s0 = 0.f, s1 = 0.f, t0 = 0.f, t1 = 0.f;
  float u0 = 0.f, u1 = 0.f, v0 = 0.f, v1 = 0.f;
  int e = 0;
  for (; e + 3 < dloop; e += 4) {
    ushort4 q = *reinterpret_cast<const ushort4*>(csr + beg + e);
    float2 a = __half22float2(*reinterpret_cast<const __half2*>(t16 + (size_t)q.x * 128 + lane * 2));
    float2 b = __half22float2(*reinterpret_cast<const __half2*>(t16 + (size_t)q.y * 128 + lane * 2));
    float2 c = __half22float2(*reinterpret_cast<const __half2*>(t16 + (size_t)q.z * 128 + lane * 2));
    float2 d = __half22float2(*reinterpret_cast<const __half2*>(t16 + (size_t)q.w * 128 + lane * 2));
    s0 += a.x; s1 += a.y; t0 += b.x; t1 += b.y;
    u0 += c.x; u1 += c.y; v0 += d.x; v1 += d.y;
  }
  for (; e < dloop; ++e) {
    int i0 = csr[beg + e];
    float2 a = __half22float2(*reinterpret_cast<const __half2*>(t16 + (size_t)i0 * 128 + lane * 2));
    s0 += a.x; s1 += a.y;
  }
  float2 sm = make_float2(s0 + t0 + u0 + v0, s1 + t1 + u1 + v1);
  float2 xv;
  if (SELF32) {
    xv = *reinterpret_cast<const float2*>(xself + (size_t)node * 128 + lane * 2);
  } else {
    xv = __half22float2(*reinterpret_cast<const __half2*>(t16 + (size_t)node * 128 + lane * 2));
  }
  float2 o = make_float2(fmaf(sm.x, inv, xv.x), fmaf(sm.y, inv, xv.y));
  *reinterpret_cast<float2*>(out + (size_t)node * 128 + lane * 2) = o;
}

// ---------------- MLP building blocks, BM=160 rows/block, 512 threads (8 waves) ----------------
// stage X tile (160 rows x 128) as bf16 hi/lo into swizzled LDS
__device__ __forceinline__ void stage_xT(const float* __restrict__ X, int m0, int tid,
                                         char* ahi, char* alo, int M) {
  #pragma unroll
  for (int it = 0; it < 10; ++it) {
    int f = tid + it * 512;                 // covers 160*32 float4s
    int row = f >> 5, c = f & 31;
    float4 v = make_float4(0.f, 0.f, 0.f, 0.f);
    if (m0 + row < M)
      v = *reinterpret_cast<const float4*>(X + (size_t)(m0 + row) * 128 + c * 4);
    ushort4 hi, lo;
    float fh;
    hi.x = bf16_rne(v.x); fh = __uint_as_float((unsigned)hi.x << 16); lo.x = bf16_rne(v.x - fh);
    hi.y = bf16_rne(v.y); fh = __uint_as_float((unsigned)hi.y << 16); lo.y = bf16_rne(v.y - fh);
    hi.z = bf16_rne(v.z); fh = __uint_as_float((unsigned)hi.z << 16); lo.z = bf16_rne(v.z - fh);
    hi.w = bf16_rne(v.w); fh = __uint_as_float((unsigned)hi.w << 16); lo.w = bf16_rne(v.w - fh);
    int bo = swz(row, c * 8);
    *reinterpret_cast<ushort4*>(ahi + bo) = hi;
    *reinterpret_cast<ushort4*>(alo + bo) = lo;
  }
}

// stage W (NR rows x 128 bf16, hi+lo) into swizzled LDS via async DMA (8 waves)
template <int NR>
__device__ __forceinline__ void stage_w(const unsigned short* __restrict__ gh,
                                        const unsigned short* __restrict__ gl,
                                        char* WH, char* WL, int w, int lane) {
  constexpr int CH = NR / 32;               // 1KB chunks per wave (8 waves)
  #pragma unroll
  for (int k = 0; k < CH; ++k) {
    int base = w * (NR * 32) + k * 1024;    // wave-uniform byte offset
    int ofs = base + lane * 16;
    int row = ofs >> 8;
    int g = ofs ^ ((row & 7) << 4);         // inverse-swizzle source (involution)
    gload_lds16((const char*)gh + g, WH + base);
    gload_lds16((const char*)gl + g, WL + base);
  }
}

// GEMM: each wave covers 16 output cols (w*16..w*16+15) x 160 rows; W,A in swizzled LDS
__device__ __forceinline__ void gemmT(const char* ahi, const char* alo,
                                      const char* wh, const char* wl,
                                      int w, int lrow, int lg, f32x4 (&acc)[10]) {
  #pragma unroll
  for (int i = 0; i < 10; ++i) acc[i] = (f32x4){0.f, 0.f, 0.f, 0.f};
  const int col = w * 16 + lrow;
  #pragma unroll
  for (int kk = 0; kk < 4; ++kk) {
    int wo = swz(col, kk * 64 + lg * 16);
    bf16x8 bh = *reinterpret_cast<const bf16x8*>(wh + wo);
    bf16x8 bl = *reinterpret_cast<const bf16x8*>(wl + wo);
    #pragma unroll
    for (int i = 0; i < 10; ++i) {
      int bo = swz(i * 16 + lrow, kk * 64 + lg * 16);
      bf16x8 ah = *reinterpret_cast<const bf16x8*>(ahi + bo);
      bf16x8 al = *reinterpret_cast<const bf16x8*>(alo + bo);
      acc[i] = __builtin_amdgcn_mfma_f32_16x16x32_bf16(ah, bh, acc[i], 0, 0, 0);
      acc[i] = __builtin_amdgcn_mfma_f32_16x16x32_bf16(al, bh, acc[i], 0, 0, 0);
      acc[i] = __builtin_amdgcn_mfma_f32_16x16x32_bf16(ah, bl, acc[i], 0, 0, 0);
    }
  }
}

// h = relu(acc + bias) -> LDS bf16 hi/lo (wave's 16 cols)
__device__ __forceinline__ void store_hT(char* ahi, char* alo, const float* __restrict__ bias,
                                         int w, int lrow, int lg, f32x4 (&acc)[10]) {
  const int col = w * 16 + lrow;
  const float b = bias[col];
  #pragma unroll
  for (int i = 0; i < 10; ++i) {
    #pragma unroll
    for (int r = 0; r < 4; ++r) {
      float v = fmaxf(acc[i][r] + b, 0.f);
      int row = i * 16 + lg * 4 + r;
      unsigned short h = bf16_rne(v);
      float fh = __uint_as_float((unsigned)h << 16);
      unsigned short l2 = bf16_rne(v - fh);
      int bo = swz(row, col * 2);
      *reinterpret_cast<unsigned short*>(ahi + bo) = h;
      *reinterpret_cast<unsigned short*>(alo + bo) = l2;
    }
  }
}

// ---------------- mlp1: bufA -> relu(relu(X W1a^T+b1a) W1b^T + b1b) -> fp16 table ----------------
__global__ __launch_bounds__(512, 2)
void mlp1_kernel(const float* __restrict__ X, const unsigned short* __restrict__ p,
                 const float* __restrict__ b1a, const float* __restrict__ b1b,
                 __half* __restrict__ Y, int M) {
  __shared__ __align__(16) unsigned short Ahi[160 * 128];  // 40 KB
  __shared__ __align__(16) unsigned short Alo[160 * 128];  // 40 KB
  __shared__ __align__(16) unsigned short WHs[128 * 128];  // 32 KB
  __shared__ __align__(16) unsigned short WLs[128 * 128];  // 32 KB
  char* ahi = (char*)Ahi; char* alo = (char*)Alo;
  char* wh = (char*)WHs;  char* wl = (char*)WLs;
  const int tid = threadIdx.x;
  const int w = tid >> 6, l = tid & 63;
  const int lrow = l & 15, lg = l >> 4;
  const int m0 = blockIdx.x * BM;

  stage_w<128>(p + 0, p + 16384, wh, wl, w, l);            // W1a
  stage_xT(X, m0, tid, ahi, alo, M);
  __syncthreads();

  f32x4 acc[10];
  gemmT(ahi, alo, wh, wl, w, lrow, lg, acc);
  __syncthreads();

  stage_w<128>(p + 32768, p + 49152, wh, wl, w, l);        // W1b
  store_hT(ahi, alo, b1a, w, lrow, lg, acc);
  __syncthreads();

  gemmT(ahi, alo, wh, wl, w, lrow, lg, acc);

  const int col = w * 16 + lrow;
  const float b = b1b[col];
  #pragma unroll
  for (int i = 0; i < 10; ++i) {
    #pragma unroll
    for (int r = 0; r < 4; ++r) {
      float v = fmaxf(acc[i][r] + b, 0.f);
      int row = m0 + i * 16 + lg * 4 + r;
      if (row < M) Y[(size_t)row * 128 + col] = __float2half_rn(v);
    }
  }
}

// ---------------- mlp2+head: bufA -> layer2 MLP -> head (4 GEMMs) -> d_out ----------------
__global__ __launch_bounds__(512, 2)
void mlp2head_kernel(const float* __restrict__ X, const unsigned short* __restrict__ p,
                     const float* __restrict__ b2a, const float* __restrict__ b2b,
                     const float* __restrict__ b3a, const float* __restrict__ b3b,
                     float* __restrict__ Y, int M) {
  __shared__ __align__(16) unsigned short Ahi[160 * 128];
  __shared__ __align__(16) unsigned short Alo[160 * 128];
  __shared__ __align__(16) unsigned short WHs[128 * 128];
  __shared__ __align__(16) unsigned short WLs[128 * 128];
  char* ahi = (char*)Ahi; char* alo = (char*)Alo;
  char* wh = (char*)WHs;  char* wl = (char*)WLs;
  const int tid = threadIdx.x;
  const int w = tid >> 6, l = tid & 63;
  const int lrow = l & 15, lg = l >> 4;
  const int m0 = blockIdx.x * BM;

  stage_w<128>(p + 65536, p + 81920, wh, wl, w, l);        // W2a
  stage_xT(X, m0, tid, ahi, alo, M);
  __syncthreads();

  f32x4 acc[10];
  gemmT(ahi, alo, wh, wl, w, lrow, lg, acc);
  __syncthreads();

  stage_w<128>(p + 98304, p + 114688, wh, wl, w, l);       // W2b
  store_hT(ahi, alo, b2a, w, lrow, lg, acc);
  __syncthreads();

  gemmT(ahi, alo, wh, wl, w, lrow, lg, acc);
  __syncthreads();

  stage_w<128>(p + 131072, p + 147456, wh, wl, w, l);      // W3a
  store_hT(ahi, alo, b2b, w, lrow, lg, acc);               // layer-2 outer relu
  __syncthreads();

  gemmT(ahi, alo, wh, wl, w, lrow, lg, acc);
  __syncthreads();

  stage_w<64>(p + 163840, p + 172032, wh, wl, w, l);       // W3b (64 rows)
  store_hT(ahi, alo, b3a, w, lrow, lg, acc);               // head inner relu
  __syncthreads();

  if (w < 4) {                                             // head: 64 output cols
    f32x4 acc2[10];
    gemmT(ahi, alo, wh, wl, w, lrow, lg, acc2);
    const int col = w * 16 + lrow;
    const float b = b3b[col];
    #pragma unroll
    for (int i = 0; i < 10; ++i) {
      #pragma unroll
      for (int r = 0; r < 4; ++r) {
        float v = acc2[i][r] + b;
        int row = m0 + i * 16 + lg * 4 + r;
        if (row < M) Y[(size_t)row * 64 + col] = v;
      }
    }
  }
}

// ---------------- launch ----------------
extern "C" void kernel_launch(void* const* d_in, const int* in_sizes, int n_in,
                              void* d_out, int out_size, void* d_ws, size_t ws_size,
                              hipStream_t stream) {
  const float* feat = (const float*)d_in[0];
  const int*   esrc = (const int*)d_in[1];
  const int*   edst = (const int*)d_in[2];
  const float* W1a = (const float*)d_in[3];  const float* b1a = (const float*)d_in[4];
  const float* W1b = (const float*)d_in[5];  const float* b1b = (const float*)d_in[6];
  const float* W2a = (const float*)d_in[7];  const float* b2a = (const float*)d_in[8];
  const float* W2b = (const float*)d_in[9];  const float* b2b = (const float*)d_in[10];
  const float* W3a = (const float*)d_in[11]; const float* b3a = (const float*)d_in[12];
  const float* W3b = (const float*)d_in[13]; const float* b3b = (const float*)d_in[14];

  char* ws = (char*)d_ws;
  float*  bufA = (float*)(ws + OFF_BUFA);
  __half* t16  = (__half*)(ws + OFF_T16);
  int*    cnt  = (int*)(ws + OFF_CNT);
  unsigned short* p   = (unsigned short*)(ws + OFF_W);
  unsigned short* csr = (unsigned short*)(ws + OFF_CSR);

  hipMemsetAsync(cnt, 0, 200000, stream);

  scatter16<<<NB_EDGE, 256, 0, stream>>>(esrc, edst, cnt, csr);
  conv_kernel<<<NB_W + NB_FEAT, 256, 0, stream>>>(W1a, W1b, W2a, W2b, W3a, W3b, p, feat, t16);

  const int AB = (N_NODES + 3) / 4;     // 12500

  // layer 1: agg(feat via fp16 table, self fp32) -> bufA; mlp1 -> t16 (fp16)
  agg_kernel<true><<<AB, 256, 0, stream>>>(t16, feat, csr, cnt, bufA);
  mlp1_kernel<<<GB_MLP, 512, 0, stream>>>(bufA, p, b1a, b1b, t16, N_NODES);

  // layer 2 + head: agg(t16) -> bufA; mlp2+head -> d_out
  agg_kernel<false><<<AB, 256, 0, stream>>>(t16, feat, csr, cnt, bufA);
  mlp2head_kernel<<<GB_MLP, 512, 0, stream>>>(bufA, p, b2a, b2b, b3a, b3b,
                                              (float*)d_out, N_NODES);
}

// Round 13
// 209.526 us; speedup vs baseline: 1.1203x; 1.1203x over previous
//
#include <hip/hip_runtime.h>
#include <hip/hip_fp16.h>

#define N_NODES 50000
#define N_EDGES 800000

typedef __attribute__((ext_vector_type(8))) short s16x8;
typedef _Float16 f16x8 __attribute__((ext_vector_type(8)));
typedef __attribute__((ext_vector_type(4))) float f32x4;

// ---------------- workspace layout (bytes) ----------------
#define OFF_BUFA   0UL          // 25,600,000  agg output fp32 [50000][128]
#define OFF_T16    25600000UL   // 12,800,000  fp16 feature table [50000][128]
#define OFF_CNT    38400000UL   //    200,000  degree counts
#define OFF_W      38600064UL   //    363,264  fp16 hi/lo-scaled weight pool + f32 biases
#define OFF_CSR    38963328UL   //  6,400,000  padded CSR, ushort, 64 slots/node

#define NB_EDGE 3125   // 800000/256
#define NB_WB   355    // ceil(90816/256): 90112 weights + 704 biases
#define NB_FEAT 6250   // 6,400,000/(256*4)

#define INV2048 4.8828125e-4f

__device__ __forceinline__ int swz(int row, int b) {
  return (row * 256 + b) ^ ((row & 7) << 4);
}

// ---------------- prep: scatter + weight convert + bias pack + feat->fp16 ----------------
__global__ __launch_bounds__(256)
void prep_kernel(const int* __restrict__ esrc, const int* __restrict__ edst,
                 int* __restrict__ cnt, unsigned short* __restrict__ csr,
                 const float* __restrict__ W1a, const float* __restrict__ b1a,
                 const float* __restrict__ W1b, const float* __restrict__ b1b,
                 const float* __restrict__ W2a, const float* __restrict__ b2a,
                 const float* __restrict__ W2b, const float* __restrict__ b2b,
                 const float* __restrict__ W3a, const float* __restrict__ b3a,
                 const float* __restrict__ W3b, const float* __restrict__ b3b,
                 unsigned short* __restrict__ pool,
                 const float* __restrict__ feat, __half* __restrict__ t16) {
  const int b = blockIdx.x;
  const int tid = threadIdx.x;
  if (b < NB_EDGE) {
    int i = b * 256 + tid;                  // covers 800000 exactly
    int d = edst[i];
    int pos = atomicAdd(&cnt[d], 1);
    if (pos < 64) csr[(d << 6) + pos] = (unsigned short)esrc[i];
  } else if (b < NB_EDGE + NB_WB) {
    int i = (b - NB_EDGE) * 256 + tid;
    if (i < 90112) {                        // weights -> fp16 hi + fp16 (lo*2048)
      const float* s;
      int base, local, msize;
      if (i < 16384)      { s = W1a; base = 0;      local = i;          msize = 16384; }
      else if (i < 32768) { s = W1b; base = 32768;  local = i - 16384;  msize = 16384; }
      else if (i < 49152) { s = W2a; base = 65536;  local = i - 32768;  msize = 16384; }
      else if (i < 65536) { s = W2b; base = 98304;  local = i - 49152;  msize = 16384; }
      else if (i < 81920) { s = W3a; base = 131072; local = i - 65536;  msize = 16384; }
      else                { s = W3b; base = 163840; local = i - 81920;  msize = 8192;  }
      float f = s[local];
      __half h = __float2half_rn(f);
      float fh = __half2float(h);
      __half l = __float2half_rn((f - fh) * 2048.0f);
      pool[base + local] = __half_as_ushort(h);
      pool[base + msize + local] = __half_as_ushort(l);
    } else if (i < 90816) {                 // biases -> f32 pool @ half-index 180224
      int j = i - 90112;
      const float* s; int o;
      if (j < 128)      { s = b1a; o = j; }
      else if (j < 256) { s = b1b; o = j - 128; }
      else if (j < 384) { s = b2a; o = j - 256; }
      else if (j < 512) { s = b2b; o = j - 384; }
      else if (j < 640) { s = b3a; o = j - 512; }
      else              { s = b3b; o = j - 640; }
      ((float*)(pool + 180224))[j] = s[o];
    }
  } else {
    int i = (b - NB_EDGE - NB_WB) * 1024 + tid * 4;   // covers 6,400,000
    float4 v = *reinterpret_cast<const float4*>(feat + i);
    ushort4 h;
    h.x = __half_as_ushort(__float2half_rn(v.x));
    h.y = __half_as_ushort(__float2half_rn(v.y));
    h.z = __half_as_ushort(__float2half_rn(v.z));
    h.w = __half_as_ushort(__float2half_rn(v.w));
    *reinterpret_cast<ushort4*>((unsigned short*)t16 + i) = h;
  }
}

// ---------------- aggregation: out[v] = self[v] + inv_deg * sum t16[src]  (fp32 out) ----------------
template <bool SELF32>
__global__ __launch_bounds__(256)
void agg_kernel(const __half* __restrict__ t16, const float* __restrict__ xself,
                const unsigned short* __restrict__ csr, const int* __restrict__ cnt,
                float* __restrict__ out) {
  int node = blockIdx.x * 4 + (threadIdx.x >> 6);
  if (node >= N_NODES) return;
  const int lane = threadIdx.x & 63;
  int deg = cnt[node];
  int dloop = min(deg, 64);
  int beg = node << 6;
  float inv = 1.0f / fmaxf((float)deg, 1.0f);

  float s0 = 0.f, s1 = 0.f, t0 = 0.f, t1 = 0.f;
  float u0 = 0.f, u1 = 0.f, v0 = 0.f, v1 = 0.f;
  int e = 0;
  for (; e + 3 < dloop; e += 4) {
    ushort4 q = *reinterpret_cast<const ushort4*>(csr + beg + e);
    float2 a = __half22float2(*reinterpret_cast<const __half2*>(t16 + (size_t)q.x * 128 + lane * 2));
    float2 b = __half22float2(*reinterpret_cast<const __half2*>(t16 + (size_t)q.y * 128 + lane * 2));
    float2 c = __half22float2(*reinterpret_cast<const __half2*>(t16 + (size_t)q.z * 128 + lane * 2));
    float2 d = __half22float2(*reinterpret_cast<const __half2*>(t16 + (size_t)q.w * 128 + lane * 2));
    s0 += a.x; s1 += a.y; t0 += b.x; t1 += b.y;
    u0 += c.x; u1 += c.y; v0 += d.x; v1 += d.y;
  }
  for (; e < dloop; ++e) {
    int i0 = csr[beg + e];
    float2 a = __half22float2(*reinterpret_cast<const __half2*>(t16 + (size_t)i0 * 128 + lane * 2));
    s0 += a.x; s1 += a.y;
  }
  float2 sm = make_float2(s0 + t0 + u0 + v0, s1 + t1 + u1 + v1);
  float2 xv;
  if (SELF32) {
    xv = *reinterpret_cast<const float2*>(xself + (size_t)node * 128 + lane * 2);
  } else {
    xv = __half22float2(*reinterpret_cast<const __half2*>(t16 + (size_t)node * 128 + lane * 2));
  }
  float2 o = make_float2(fmaf(sm.x, inv, xv.x), fmaf(sm.y, inv, xv.y));
  *reinterpret_cast<float2*>(out + (size_t)node * 128 + lane * 2) = o;
}

// ---------------- MLP building blocks: BM=64, 256 threads (4 waves), fp16 scheme B ----------------
// stage X (64 rows x 128) fp32 -> single fp16 swizzled LDS table (16 KB)
__device__ __forceinline__ void stage_x(const float* __restrict__ X, int m0, int tid,
                                        char* a16, int M) {
  #pragma unroll
  for (int it = 0; it < 4; ++it) {
    int f = tid + it * 256;                 // 64 rows x 16 chunks of 8 halfs
    int row = f >> 4, c8 = (f & 15) * 8;
    float4 v0 = make_float4(0.f, 0.f, 0.f, 0.f), v1 = v0;
    if (m0 + row < M) {
      const float* xp = X + (size_t)(m0 + row) * 128 + c8;
      v0 = *reinterpret_cast<const float4*>(xp);
      v1 = *reinterpret_cast<const float4*>(xp + 4);
    }
    f16x8 hv;
    hv[0] = (_Float16)v0.x; hv[1] = (_Float16)v0.y; hv[2] = (_Float16)v0.z; hv[3] = (_Float16)v0.w;
    hv[4] = (_Float16)v1.x; hv[5] = (_Float16)v1.y; hv[6] = (_Float16)v1.z; hv[7] = (_Float16)v1.w;
    *reinterpret_cast<f16x8*>(a16 + swz(row, c8 * 2)) = hv;
  }
}

// one GEMM stage: acc_h += A x Wh ; acc_l += A x (Wlo*2048). A fp16 LDS, W fp16 global (L2-hot).
template <int NB>
__device__ __forceinline__ void gemm_stage(const char* a16,
                                           const unsigned short* __restrict__ wh,
                                           const unsigned short* __restrict__ wl,
                                           int w, int lrow, int lg,
                                           f32x4 (&acch)[4][NB], f32x4 (&accl)[4][NB]) {
  f16x8 bh[NB][4], bl[NB][4];
  #pragma unroll
  for (int nb = 0; nb < NB; ++nb) {
    int col = w * (16 * NB) + nb * 16 + lrow;
    #pragma unroll
    for (int kk = 0; kk < 4; ++kk) {
      int idx = col * 128 + kk * 32 + lg * 8;
      bh[nb][kk] = *reinterpret_cast<const f16x8*>(wh + idx);
      bl[nb][kk] = *reinterpret_cast<const f16x8*>(wl + idx);
    }
  }
  #pragma unroll
  for (int i = 0; i < 4; ++i)
    #pragma unroll
    for (int nb = 0; nb < NB; ++nb) {
      acch[i][nb] = (f32x4){0.f, 0.f, 0.f, 0.f};
      accl[i][nb] = (f32x4){0.f, 0.f, 0.f, 0.f};
    }
  #pragma unroll
  for (int kk = 0; kk < 4; ++kk) {
    #pragma unroll
    for (int i = 0; i < 4; ++i) {
      f16x8 a = *reinterpret_cast<const f16x8*>(a16 + swz(i * 16 + lrow, kk * 64 + lg * 16));
      #pragma unroll
      for (int nb = 0; nb < NB; ++nb) {
        acch[i][nb] = __builtin_amdgcn_mfma_f32_16x16x32_f16(a, bh[nb][kk], acch[i][nb], 0, 0, 0);
        accl[i][nb] = __builtin_amdgcn_mfma_f32_16x16x32_f16(a, bl[nb][kk], accl[i][nb], 0, 0, 0);
      }
    }
  }
}

// h = relu(acc_h + acc_l/2048 + bias) -> fp16 LDS table (NB=2, 128 cols)
__device__ __forceinline__ void store_h(char* a16, const float* __restrict__ bias,
                                        int w, int lrow, int lg,
                                        f32x4 (&acch)[4][2], f32x4 (&accl)[4][2]) {
  #pragma unroll
  for (int i = 0; i < 4; ++i) {
    #pragma unroll
    for (int nb = 0; nb < 2; ++nb) {
      int col = w * 32 + nb * 16 + lrow;
      float b = bias[col];
      #pragma unroll
      for (int r = 0; r < 4; ++r) {
        float v = fmaxf(fmaf(accl[i][nb][r], INV2048, acch[i][nb][r]) + b, 0.f);
        int row = i * 16 + lg * 4 + r;
        *reinterpret_cast<unsigned short*>(a16 + swz(row, col * 2)) =
            __half_as_ushort(__float2half_rn(v));
      }
    }
  }
}

// ---------------- mlp1: bufA -> relu(relu(X W1a^T+b1a) W1b^T + b1b) -> fp16 table ----------------
__global__ __launch_bounds__(256, 2)
void mlp1_kernel(const float* __restrict__ X, const unsigned short* __restrict__ p,
                 __half* __restrict__ Y, int M) {
  __shared__ __align__(16) unsigned short A16[64 * 128];   // 16 KB
  char* a16 = (char*)A16;
  const float* biases = (const float*)(p + 180224);
  const int tid = threadIdx.x;
  const int w = tid >> 6, l = tid & 63;
  const int lrow = l & 15, lg = l >> 4;
  const int m0 = blockIdx.x * 64;

  stage_x(X, m0, tid, a16, M);
  __syncthreads();

  f32x4 acch[4][2], accl[4][2];
  gemm_stage<2>(a16, p + 0, p + 16384, w, lrow, lg, acch, accl);       // W1a
  __syncthreads();
  store_h(a16, biases + 0, w, lrow, lg, acch, accl);                   // b1a
  __syncthreads();
  gemm_stage<2>(a16, p + 32768, p + 49152, w, lrow, lg, acch, accl);   // W1b

  #pragma unroll
  for (int i = 0; i < 4; ++i) {
    #pragma unroll
    for (int nb = 0; nb < 2; ++nb) {
      int col = w * 32 + nb * 16 + lrow;
      float b = biases[128 + col];                                     // b1b
      #pragma unroll
      for (int r = 0; r < 4; ++r) {
        float v = fmaxf(fmaf(accl[i][nb][r], INV2048, acch[i][nb][r]) + b, 0.f);
        int row = m0 + i * 16 + lg * 4 + r;
        if (row < M) Y[(size_t)row * 128 + col] = __float2half_rn(v);
      }
    }
  }
}

// ---------------- mlp2+head: bufA -> layer2 MLP + head (4 GEMMs) -> d_out ----------------
__global__ __launch_bounds__(256, 2)
void mlp2head_kernel(const float* __restrict__ X, const unsigned short* __restrict__ p,
                     float* __restrict__ Y, int M) {
  __shared__ __align__(16) unsigned short A16[64 * 128];   // 16 KB
  char* a16 = (char*)A16;
  const float* biases = (const float*)(p + 180224);
  const int tid = threadIdx.x;
  const int w = tid >> 6, l = tid & 63;
  const int lrow = l & 15, lg = l >> 4;
  const int m0 = blockIdx.x * 64;

  stage_x(X, m0, tid, a16, M);
  __syncthreads();

  // 3 identical stages: W2a/b2a, W2b/b2b, W3a/b3a — compact loop (I$-resident body)
  #pragma unroll 1
  for (int s = 0; s < 3; ++s) {
    const unsigned short* wh = p + 65536 + s * 32768;
    const unsigned short* wl = wh + 16384;
    f32x4 acch[4][2], accl[4][2];
    gemm_stage<2>(a16, wh, wl, w, lrow, lg, acch, accl);
    __syncthreads();
    store_h(a16, biases + 256 + s * 128, w, lrow, lg, acch, accl);
    __syncthreads();
  }

  // head: W3b (64 cols), no relu -> d_out
  f32x4 acch[4][1], accl[4][1];
  gemm_stage<1>(a16, p + 163840, p + 172032, w, lrow, lg, acch, accl);
  #pragma unroll
  for (int i = 0; i < 4; ++i) {
    int col = w * 16 + lrow;
    float b = biases[640 + col];                                       // b3b
    #pragma unroll
    for (int r = 0; r < 4; ++r) {
      float v = fmaf(accl[i][0][r], INV2048, acch[i][0][r]) + b;
      int row = m0 + i * 16 + lg * 4 + r;
      if (row < M) Y[(size_t)row * 64 + col] = v;
    }
  }
}

// ---------------- launch ----------------
extern "C" void kernel_launch(void* const* d_in, const int* in_sizes, int n_in,
                              void* d_out, int out_size, void* d_ws, size_t ws_size,
                              hipStream_t stream) {
  const float* feat = (const float*)d_in[0];
  const int*   esrc = (const int*)d_in[1];
  const int*   edst = (const int*)d_in[2];
  const float* W1a = (const float*)d_in[3];  const float* b1a = (const float*)d_in[4];
  const float* W1b = (const float*)d_in[5];  const float* b1b = (const float*)d_in[6];
  const float* W2a = (const float*)d_in[7];  const float* b2a = (const float*)d_in[8];
  const float* W2b = (const float*)d_in[9];  const float* b2b = (const float*)d_in[10];
  const float* W3a = (const float*)d_in[11]; const float* b3a = (const float*)d_in[12];
  const float* W3b = (const float*)d_in[13]; const float* b3b = (const float*)d_in[14];

  char* ws = (char*)d_ws;
  float*  bufA = (float*)(ws + OFF_BUFA);
  __half* t16  = (__half*)(ws + OFF_T16);
  int*    cnt  = (int*)(ws + OFF_CNT);
  unsigned short* p   = (unsigned short*)(ws + OFF_W);
  unsigned short* csr = (unsigned short*)(ws + OFF_CSR);

  hipMemsetAsync(cnt, 0, 200000, stream);

  prep_kernel<<<NB_EDGE + NB_WB + NB_FEAT, 256, 0, stream>>>(
      esrc, edst, cnt, csr,
      W1a, b1a, W1b, b1b, W2a, b2a, W2b, b2b, W3a, b3a, W3b, b3b,
      p, feat, t16);

  const int AB = (N_NODES + 3) / 4;     // 12500
  const int GB = (N_NODES + 63) / 64;   // 782

  // layer 1: agg(feat, fp16 gather / fp32 self) -> bufA; mlp1 -> t16 (fp16)
  agg_kernel<true><<<AB, 256, 0, stream>>>(t16, feat, csr, cnt, bufA);
  mlp1_kernel<<<GB, 256, 0, stream>>>(bufA, p, t16, N_NODES);

  // layer 2 + head: agg(t16) -> bufA; mlp2+head -> d_out
  agg_kernel<false><<<AB, 256, 0, stream>>>(t16, feat, csr, cnt, bufA);
  mlp2head_kernel<<<GB, 256, 0, stream>>>(bufA, p, (float*)d_out, N_NODES);
}

// Round 15
// 205.447 us; speedup vs baseline: 1.1426x; 1.0199x over previous
//
#include <hip/hip_runtime.h>
#include <hip/hip_fp16.h>

#define N_NODES 50000
#define N_EDGES 800000

typedef __attribute__((ext_vector_type(8))) short s16x8;
typedef _Float16 f16x8 __attribute__((ext_vector_type(8)));
typedef __attribute__((ext_vector_type(4))) float f32x4;

// ---------------- workspace layout (bytes) ----------------
#define OFF_BUFA   0UL          // 25,600,000  agg output fp32 [50000][128]
#define OFF_T16    25600000UL   // 12,800,000  fp16 feature table [50000][128]
#define OFF_CNT    38400000UL   //  3,200,000  degree counters, PADDED 1 line (16 ints) per node
#define OFF_W      41600000UL   //    363,264  fp16 hi/lo-scaled weight pool + f32 biases
#define OFF_CSR    41963264UL   //  6,400,000  padded CSR, ushort, 64 slots/node

#define NB_EDGE 3125   // 800000/256
#define NB_WB   355    // ceil(90816/256): 90112 weights + 704 biases
#define NB_FEAT 6250   // 6,400,000/(256*4)

#define INV2048 4.8828125e-4f

__device__ __forceinline__ int swz(int row, int b) {
  return (row * 256 + b) ^ ((row & 7) << 4);
}

// ---------------- prep: scatter + weight convert + bias pack + feat->fp16 ----------------
__global__ __launch_bounds__(256)
void prep_kernel(const int* __restrict__ esrc, const int* __restrict__ edst,
                 int* __restrict__ cnt, unsigned short* __restrict__ csr,
                 const float* __restrict__ W1a, const float* __restrict__ b1a,
                 const float* __restrict__ W1b, const float* __restrict__ b1b,
                 const float* __restrict__ W2a, const float* __restrict__ b2a,
                 const float* __restrict__ W2b, const float* __restrict__ b2b,
                 const float* __restrict__ W3a, const float* __restrict__ b3a,
                 const float* __restrict__ W3b, const float* __restrict__ b3b,
                 unsigned short* __restrict__ pool,
                 const float* __restrict__ feat, __half* __restrict__ t16) {
  const int b = blockIdx.x;
  const int tid = threadIdx.x;
  if (b < NB_EDGE) {
    int i = b * 256 + tid;                  // covers 800000 exactly
    int d = edst[i];
    int pos = atomicAdd(&cnt[d << 4], 1);   // padded: 1 cache line per counter
    if (pos < 64) csr[(d << 6) + pos] = (unsigned short)esrc[i];
  } else if (b < NB_EDGE + NB_WB) {
    int i = (b - NB_EDGE) * 256 + tid;
    if (i < 90112) {                        // weights -> fp16 hi + fp16 (lo*2048)
      const float* s;
      int base, local, msize;
      if (i < 16384)      { s = W1a; base = 0;      local = i;          msize = 16384; }
      else if (i < 32768) { s = W1b; base = 32768;  local = i - 16384;  msize = 16384; }
      else if (i < 49152) { s = W2a; base = 65536;  local = i - 32768;  msize = 16384; }
      else if (i < 65536) { s = W2b; base = 98304;  local = i - 49152;  msize = 16384; }
      else if (i < 81920) { s = W3a; base = 131072; local = i - 65536;  msize = 16384; }
      else                { s = W3b; base = 163840; local = i - 81920;  msize = 8192;  }
      float f = s[local];
      __half h = __float2half_rn(f);
      float fh = __half2float(h);
      __half l = __float2half_rn((f - fh) * 2048.0f);
      pool[base + local] = __half_as_ushort(h);
      pool[base + msize + local] = __half_as_ushort(l);
    } else if (i < 90816) {                 // biases -> f32 pool @ half-index 180224
      int j = i - 90112;
      const float* s; int o;
      if (j < 128)      { s = b1a; o = j; }
      else if (j < 256) { s = b1b; o = j - 128; }
      else if (j < 384) { s = b2a; o = j - 256; }
      else if (j < 512) { s = b2b; o = j - 384; }
      else if (j < 640) { s = b3a; o = j - 512; }
      else              { s = b3b; o = j - 640; }
      ((float*)(pool + 180224))[j] = s[o];
    }
  } else {
    int i = (b - NB_EDGE - NB_WB) * 1024 + tid * 4;   // covers 6,400,000
    float4 v = *reinterpret_cast<const float4*>(feat + i);
    ushort4 h;
    h.x = __half_as_ushort(__float2half_rn(v.x));
    h.y = __half_as_ushort(__float2half_rn(v.y));
    h.z = __half_as_ushort(__float2half_rn(v.z));
    h.w = __half_as_ushort(__float2half_rn(v.w));
    *reinterpret_cast<ushort4*>((unsigned short*)t16 + i) = h;
  }
}

// ---------------- aggregation: out[v] = self[v] + inv_deg * sum t16[src]  (fp32 out) ----------------
template <bool SELF32>
__global__ __launch_bounds__(256)
void agg_kernel(const __half* __restrict__ t16, const float* __restrict__ xself,
                const unsigned short* __restrict__ csr, const int* __restrict__ cnt,
                float* __restrict__ out) {
  int node = blockIdx.x * 4 + (threadIdx.x >> 6);
  if (node >= N_NODES) return;
  const int lane = threadIdx.x & 63;
  int deg = cnt[node << 4];
  int dloop = min(deg, 64);
  int beg = node << 6;
  float inv = 1.0f / fmaxf((float)deg, 1.0f);

  float s0 = 0.f, s1 = 0.f, t0 = 0.f, t1 = 0.f;
  float u0 = 0.f, u1 = 0.f, v0 = 0.f, v1 = 0.f;
  int e = 0;
  for (; e + 3 < dloop; e += 4) {
    ushort4 q = *reinterpret_cast<const ushort4*>(csr + beg + e);
    float2 a = __half22float2(*reinterpret_cast<const __half2*>(t16 + (size_t)q.x * 128 + lane * 2));
    float2 b = __half22float2(*reinterpret_cast<const __half2*>(t16 + (size_t)q.y * 128 + lane * 2));
    float2 c = __half22float2(*reinterpret_cast<const __half2*>(t16 + (size_t)q.z * 128 + lane * 2));
    float2 d = __half22float2(*reinterpret_cast<const __half2*>(t16 + (size_t)q.w * 128 + lane * 2));
    s0 += a.x; s1 += a.y; t0 += b.x; t1 += b.y;
    u0 += c.x; u1 += c.y; v0 += d.x; v1 += d.y;
  }
  for (; e < dloop; ++e) {
    int i0 = csr[beg + e];
    float2 a = __half22float2(*reinterpret_cast<const __half2*>(t16 + (size_t)i0 * 128 + lane * 2));
    s0 += a.x; s1 += a.y;
  }
  float2 sm = make_float2(s0 + t0 + u0 + v0, s1 + t1 + u1 + v1);
  float2 xv;
  if (SELF32) {
    xv = *reinterpret_cast<const float2*>(xself + (size_t)node * 128 + lane * 2);
  } else {
    xv = __half22float2(*reinterpret_cast<const __half2*>(t16 + (size_t)node * 128 + lane * 2));
  }
  float2 o = make_float2(fmaf(sm.x, inv, xv.x), fmaf(sm.y, inv, xv.y));
  *reinterpret_cast<float2*>(out + (size_t)node * 128 + lane * 2) = o;
}

// ---------------- MLP building blocks: BM=64, 256 threads (4 waves), fp16 scheme B ----------------
// stage X (64 rows x 128) fp32 -> single fp16 swizzled LDS table (16 KB)
__device__ __forceinline__ void stage_x(const float* __restrict__ X, int m0, int tid,
                                        char* a16, int M) {
  #pragma unroll
  for (int it = 0; it < 4; ++it) {
    int f = tid + it * 256;                 // 64 rows x 16 chunks of 8 halfs
    int row = f >> 4, c8 = (f & 15) * 8;
    float4 v0 = make_float4(0.f, 0.f, 0.f, 0.f), v1 = v0;
    if (m0 + row < M) {
      const float* xp = X + (size_t)(m0 + row) * 128 + c8;
      v0 = *reinterpret_cast<const float4*>(xp);
      v1 = *reinterpret_cast<const float4*>(xp + 4);
    }
    f16x8 hv;
    hv[0] = (_Float16)v0.x; hv[1] = (_Float16)v0.y; hv[2] = (_Float16)v0.z; hv[3] = (_Float16)v0.w;
    hv[4] = (_Float16)v1.x; hv[5] = (_Float16)v1.y; hv[6] = (_Float16)v1.z; hv[7] = (_Float16)v1.w;
    *reinterpret_cast<f16x8*>(a16 + swz(row, c8 * 2)) = hv;
  }
}

// one GEMM stage: acc_h += A x Wh ; acc_l += A x (Wlo*2048). A fp16 LDS, W fp16 global (L2-hot).
template <int NB>
__device__ __forceinline__ void gemm_stage(const char* a16,
                                           const unsigned short* __restrict__ wh,
                                           const unsigned short* __restrict__ wl,
                                           int w, int lrow, int lg,
                                           f32x4 (&acch)[4][NB], f32x4 (&accl)[4][NB]) {
  f16x8 bh[NB][4], bl[NB][4];
  #pragma unroll
  for (int nb = 0; nb < NB; ++nb) {
    int col = w * (16 * NB) + nb * 16 + lrow;
    #pragma unroll
    for (int kk = 0; kk < 4; ++kk) {
      int idx = col * 128 + kk * 32 + lg * 8;
      bh[nb][kk] = *reinterpret_cast<const f16x8*>(wh + idx);
      bl[nb][kk] = *reinterpret_cast<const f16x8*>(wl + idx);
    }
  }
  #pragma unroll
  for (int i = 0; i < 4; ++i)
    #pragma unroll
    for (int nb = 0; nb < NB; ++nb) {
      acch[i][nb] = (f32x4){0.f, 0.f, 0.f, 0.f};
      accl[i][nb] = (f32x4){0.f, 0.f, 0.f, 0.f};
    }
  #pragma unroll
  for (int kk = 0; kk < 4; ++kk) {
    #pragma unroll
    for (int i = 0; i < 4; ++i) {
      f16x8 a = *reinterpret_cast<const f16x8*>(a16 + swz(i * 16 + lrow, kk * 64 + lg * 16));
      #pragma unroll
      for (int nb = 0; nb < NB; ++nb) {
        acch[i][nb] = __builtin_amdgcn_mfma_f32_16x16x32_f16(a, bh[nb][kk], acch[i][nb], 0, 0, 0);
        accl[i][nb] = __builtin_amdgcn_mfma_f32_16x16x32_f16(a, bl[nb][kk], accl[i][nb], 0, 0, 0);
      }
    }
  }
}

// h = relu(acc_h + acc_l/2048 + bias) -> fp16 LDS table (NB=2, 128 cols)
__device__ __forceinline__ void store_h(char* a16, const float* __restrict__ bias,
                                        int w, int lrow, int lg,
                                        f32x4 (&acch)[4][2], f32x4 (&accl)[4][2]) {
  #pragma unroll
  for (int i = 0; i < 4; ++i) {
    #pragma unroll
    for (int nb = 0; nb < 2; ++nb) {
      int col = w * 32 + nb * 16 + lrow;
      float b = bias[col];
      #pragma unroll
      for (int r = 0; r < 4; ++r) {
        float v = fmaxf(fmaf(accl[i][nb][r], INV2048, acch[i][nb][r]) + b, 0.f);
        int row = i * 16 + lg * 4 + r;
        *reinterpret_cast<unsigned short*>(a16 + swz(row, col * 2)) =
            __half_as_ushort(__float2half_rn(v));
      }
    }
  }
}

// ---------------- mlp1: bufA -> relu(relu(X W1a^T+b1a) W1b^T + b1b) -> fp16 table ----------------
__global__ __launch_bounds__(256, 2)
void mlp1_kernel(const float* __restrict__ X, const unsigned short* __restrict__ p,
                 __half* __restrict__ Y, int M) {
  __shared__ __align__(16) unsigned short A16[64 * 128];   // 16 KB
  char* a16 = (char*)A16;
  const float* biases = (const float*)(p + 180224);
  const int tid = threadIdx.x;
  const int w = tid >> 6, l = tid & 63;
  const int lrow = l & 15, lg = l >> 4;
  const int m0 = blockIdx.x * 64;

  stage_x(X, m0, tid, a16, M);
  __syncthreads();

  f32x4 acch[4][2], accl[4][2];
  gemm_stage<2>(a16, p + 0, p + 16384, w, lrow, lg, acch, accl);       // W1a
  __syncthreads();
  store_h(a16, biases + 0, w, lrow, lg, acch, accl);                   // b1a
  __syncthreads();
  gemm_stage<2>(a16, p + 32768, p + 49152, w, lrow, lg, acch, accl);   // W1b

  #pragma unroll
  for (int i = 0; i < 4; ++i) {
    #pragma unroll
    for (int nb = 0; nb < 2; ++nb) {
      int col = w * 32 + nb * 16 + lrow;
      float b = biases[128 + col];                                     // b1b
      #pragma unroll
      for (int r = 0; r < 4; ++r) {
        float v = fmaxf(fmaf(accl[i][nb][r], INV2048, acch[i][nb][r]) + b, 0.f);
        int row = m0 + i * 16 + lg * 4 + r;
        if (row < M) Y[(size_t)row * 128 + col] = __float2half_rn(v);
      }
    }
  }
}

// ---------------- mlp2+head: bufA -> layer2 MLP + head (4 GEMMs) -> d_out ----------------
__global__ __launch_bounds__(256, 2)
void mlp2head_kernel(const float* __restrict__ X, const unsigned short* __restrict__ p,
                     float* __restrict__ Y, int M) {
  __shared__ __align__(16) unsigned short A16[64 * 128];   // 16 KB
  char* a16 = (char*)A16;
  const float* biases = (const float*)(p + 180224);
  const int tid = threadIdx.x;
  const int w = tid >> 6, l = tid & 63;
  const int lrow = l & 15, lg = l >> 4;
  const int m0 = blockIdx.x * 64;

  stage_x(X, m0, tid, a16, M);
  __syncthreads();

  // 3 identical stages: W2a/b2a, W2b/b2b, W3a/b3a — compact loop (I$-resident body)
  #pragma unroll 1
  for (int s = 0; s < 3; ++s) {
    const unsigned short* wh = p + 65536 + s * 32768;
    const unsigned short* wl = wh + 16384;
    f32x4 acch[4][2], accl[4][2];
    gemm_stage<2>(a16, wh, wl, w, lrow, lg, acch, accl);
    __syncthreads();
    store_h(a16, biases + 256 + s * 128, w, lrow, lg, acch, accl);
    __syncthreads();
  }

  // head: W3b (64 cols), no relu -> d_out
  f32x4 acch[4][1], accl[4][1];
  gemm_stage<1>(a16, p + 163840, p + 172032, w, lrow, lg, acch, accl);
  #pragma unroll
  for (int i = 0; i < 4; ++i) {
    int col = w * 16 + lrow;
    float b = biases[640 + col];                                       // b3b
    #pragma unroll
    for (int r = 0; r < 4; ++r) {
      float v = fmaf(accl[i][0][r], INV2048, acch[i][0][r]) + b;
      int row = m0 + i * 16 + lg * 4 + r;
      if (row < M) Y[(size_t)row * 64 + col] = v;
    }
  }
}

// ---------------- launch ----------------
extern "C" void kernel_launch(void* const* d_in, const int* in_sizes, int n_in,
                              void* d_out, int out_size, void* d_ws, size_t ws_size,
                              hipStream_t stream) {
  const float* feat = (const float*)d_in[0];
  const int*   esrc = (const int*)d_in[1];
  const int*   edst = (const int*)d_in[2];
  const float* W1a = (const float*)d_in[3];  const float* b1a = (const float*)d_in[4];
  const float* W1b = (const float*)d_in[5];  const float* b1b = (const float*)d_in[6];
  const float* W2a = (const float*)d_in[7];  const float* b2a = (const float*)d_in[8];
  const float* W2b = (const float*)d_in[9];  const float* b2b = (const float*)d_in[10];
  const float* W3a = (const float*)d_in[11]; const float* b3a = (const float*)d_in[12];
  const float* W3b = (const float*)d_in[13]; const float* b3b = (const float*)d_in[14];

  char* ws = (char*)d_ws;
  float*  bufA = (float*)(ws + OFF_BUFA);
  __half* t16  = (__half*)(ws + OFF_T16);
  int*    cnt  = (int*)(ws + OFF_CNT);
  unsigned short* p   = (unsigned short*)(ws + OFF_W);
  unsigned short* csr = (unsigned short*)(ws + OFF_CSR);

  hipMemsetAsync(cnt, 0, 3200000, stream);

  prep_kernel<<<NB_EDGE + NB_WB + NB_FEAT, 256, 0, stream>>>(
      esrc, edst, cnt, csr,
      W1a, b1a, W1b, b1b, W2a, b2a, W2b, b2b, W3a, b3a, W3b, b3b,
      p, feat, t16);

  const int AB = (N_NODES + 3) / 4;     // 12500
  const int GB = (N_NODES + 63) / 64;   // 782

  // layer 1: agg(feat, fp16 gather / fp32 self) -> bufA; mlp1 -> t16 (fp16)
  agg_kernel<true><<<AB, 256, 0, stream>>>(t16, feat, csr, cnt, bufA);
  mlp1_kernel<<<GB, 256, 0, stream>>>(bufA, p, t16, N_NODES);

  // layer 2 + head: agg(t16) -> bufA; mlp2+head -> d_out
  agg_kernel<false><<<AB, 256, 0, stream>>>(t16, feat, csr, cnt, bufA);
  mlp2head_kernel<<<GB, 256, 0, stream>>>(bufA, p, (float*)d_out, N_NODES);
}